// Round 4
// baseline (3612.811 us; speedup 1.0000x reference)
//
#include <hip/hip_runtime.h>
#include <hip/hip_bf16.h>

#define NT 256
typedef unsigned short u16;

__device__ __forceinline__ u16 tobf(float x) {
  union { __hip_bfloat16 h; u16 u; } cv;
  cv.h = __float2bfloat16(x);
  return cv.u;
}
__device__ __forceinline__ float frombf(u16 u) {
  return __uint_as_float(((unsigned)u) << 16);
}

struct SeqArgs {
  const float* input;
  const float* w_start0; const float* b_start0; const float* w_mlp0; const float* b_mlp0;
  const float* w_end0;   const float* b_end0;   const float* b_lin0; const float* gamma0; const float* beta0;
  const float* w_start1; const float* b_start1; const float* w_mlp1; const float* b_mlp1;
  const float* w_end1;   const float* b_end1;   const float* b_lin1; const float* gamma1; const float* beta1;
  float* AT;    // ws: [2][64*64], AT[l][w*64+v] = a_norm[v][w]
  float* wlT;   // ws: [2][64*192], wlT[l][v*192+d] = wl[d][v]
  float* HCOL;  // ws: ring [32][192][192] fp32 h_col history (slot = S & 31)
  int*   flags; // ws: [192] progress counters
  float* out_all; float* out_hrow; float* out_hcol;
};

// prep: blocks 0,1 -> normalized adjacency transpose per layer; blocks 2,3 -> wl transpose
__global__ __launch_bounds__(256) void prep_kernel(
    const float* nv1_0, const float* nv2_0, const float* nv1_1, const float* nv2_1,
    const float* wl0, const float* wl1, float* AT, float* wlT) {
  const int tid = threadIdx.x;
  const int blk = blockIdx.x;
  if (blk < 2) {
    const float* nv1 = blk ? nv1_1 : nv1_0;
    const float* nv2 = blk ? nv2_1 : nv2_0;
    __shared__ float sP[4096];
    for (int idx = tid; idx < 4096; idx += 256) {
      int v = idx >> 6, ww = idx & 63;
      float s = 0.f;
      for (int j = 0; j < 40; ++j) s = fmaf(nv1[v*40 + j], nv2[j*64 + ww], s);
      sP[idx] = fmaxf(s, 0.f);
    }
    __syncthreads();
    if (tid < 64) {
      const int v = tid;
      float m = -1e30f;
      for (int ww = 0; ww < 64; ++ww) m = fmaxf(m, sP[v*64 + ww]);
      float s = 0.f;
      for (int ww = 0; ww < 64; ++ww) { float e = expf(sP[v*64 + ww] - m); sP[v*64 + ww] = e; s += e; }
      float inv = 1.f / s;
      float rs = 1.f;
      for (int ww = 0; ww < 64; ++ww) rs += sP[v*64 + ww] * inv;  // adj row sum
      float irs = 1.f / rs;
      for (int ww = 0; ww < 64; ++ww) {
        float a = sP[v*64 + ww] * inv + ((ww == v) ? 1.f : 0.f);
        AT[blk*4096 + ww*64 + v] = a * irs;
      }
    }
  } else {
    const int l = blk - 2;
    const float* wl = l ? wl1 : wl0;
    for (int idx = tid; idx < 12288; idx += 256) {
      int v = idx / 192, d = idx - v*192;
      wlT[l*12288 + idx] = wl[d*64 + v];
    }
  }
}

// One workgroup per row n (192 rows). Pipelined wavefront over t via flags.
__global__ __launch_bounds__(NT, 1) void seq_kernel(SeqArgs A) {
  const int n = blockIdx.x;             // 0..191
  const int w = n >> 3, b = n & 7;
  const int tid = threadIdx.x;
  const int pred = (n + 184) % 192;     // n - 8 mod 192

  __shared__ __align__(16) float sCIN[768];      // [h_row | h_col | x (up to 2ch)]
  __shared__ __align__(16) u16   sWS[64*132];    // conv weights bf16, row = i*16+c, padded to 132
  __shared__ __align__(16) float sAT[4096];      // aT[w*64+v]
  __shared__ __align__(16) float sH[2][1024];    // h buffers [c*64+v]
  __shared__ __align__(16) float sAbuf[4096];    // union: conv partials OR {G | Y | E}
  float* const sPart = sAbuf;
  float* const sG = sAbuf;          // [32][64]
  float* const sY = sAbuf + 2048;   // [6][192]
  float* const sE = sAbuf + 3200;   // [6][64]

  for (int layer = 0; layer < 2; ++layer) {
    const int in_dim = 3 + layer;
    const float* wstart = layer ? A.w_start1 : A.w_start0;
    const float* bs     = layer ? A.b_start1 : A.b_start0;
    const float* wm     = layer ? A.w_mlp1  : A.w_mlp0;
    const float* bm     = layer ? A.b_mlp1  : A.b_mlp0;
    const float* we     = layer ? A.w_end1  : A.w_end0;
    const float* be     = layer ? A.b_end1  : A.b_end0;
    const float* bl     = layer ? A.b_lin1  : A.b_lin0;
    const float* gm     = layer ? A.gamma1  : A.gamma0;
    const float* bt     = layer ? A.beta1   : A.beta0;

    // stage per-layer constants (conv weights -> bf16 in LDS)
    for (int idx = tid; idx < 16*in_dim*132; idx += NT) {
      int row = idx / 132, k = idx - row*132;
      sWS[idx] = (k < 129) ? tobf(wstart[((row & 15)*in_dim + (row >> 4))*129 + k]) : (u16)0;
    }
    for (int idx = tid; idx < 4096; idx += NT) sAT[idx] = A.AT[layer*4096 + idx];
    for (int d = tid; d < 384; d += NT) sCIN[d] = 0.f;   // h_row = h_col = 0
    __syncthreads();

    for (int t = 0; t < 71; ++t) {
      const int S = layer*71 + t;

      // (a) stage x channels
      if (layer == 0) {
        int o = t - w;
        if (o >= 0 && o < 48) {
          const float* xr = A.input + (((size_t)(b*24 + w)*48 + o)*192);
          for (int d = tid; d < 192; d += NT) sCIN[384 + d] = xr[d];
        } else {
          for (int d = tid; d < 192; d += NT) sCIN[384 + d] = 0.f;
        }
      } else {
        // layer-0 output lives in out_all (written by this same block in layer 0)
        const float* xr = A.out_all + ((size_t)n*71 + t)*384;
        for (int d = tid; d < 384; d += NT) sCIN[384 + d] = xr[d];
      }
      // (b) h_col carry from predecessor (rolled)
      if (t > 0) {
        if (tid == 0) {
          while (__hip_atomic_load(&A.flags[pred], __ATOMIC_ACQUIRE, __HIP_MEMORY_SCOPE_AGENT) < S)
            __builtin_amdgcn_s_sleep(1);
        }
        __syncthreads();
        float* hc = A.HCOL + ((size_t)((S-1) & 31)*192 + pred)*192;
        for (int d = tid; d < 192; d += NT)
          sCIN[192 + d] = __hip_atomic_load(&hc[d], __ATOMIC_RELAXED, __HIP_MEMORY_SCOPE_AGENT);
      }
      __syncthreads();

      // (c) conv partials: thread = (ci = i*16+c, vq), 16 v outputs each, 1 channel
      {
        const int ci = tid >> 2, vq = tid & 3;
        if (ci < 16*in_dim) {
          float acc[16];
#pragma unroll
          for (int j = 0; j < 16; ++j) acc[j] = 0.f;
          const float* xin = &sCIN[(ci >> 4)*192 + vq*16];
          const u16* wrow = &sWS[ci*132];
          for (int k4 = 0; k4 < 128; k4 += 4) {
            ushort4 wu = *(const ushort4*)(wrow + k4);
            float w0 = frombf(wu.x);
            float w1 = frombf(wu.y);
            float w2 = frombf(wu.z);
            float w3 = frombf(wu.w);
            union { float4 v4[5]; float f[20]; } X;
#pragma unroll
            for (int m = 0; m < 5; ++m) X.v4[m] = *(const float4*)(xin + k4 + 4*m);
#pragma unroll
            for (int j = 0; j < 16; ++j) {
              acc[j] = fmaf(w0, X.f[j],   acc[j]);
              acc[j] = fmaf(w1, X.f[j+1], acc[j]);
              acc[j] = fmaf(w2, X.f[j+2], acc[j]);
              acc[j] = fmaf(w3, X.f[j+3], acc[j]);
            }
          }
          { // tail k = 128
            float wk = frombf(wrow[128]);
            union { float4 v4[4]; float f[16]; } X;
#pragma unroll
            for (int m = 0; m < 4; ++m) X.v4[m] = *(const float4*)(xin + 128 + 4*m);
#pragma unroll
            for (int j = 0; j < 16; ++j) acc[j] = fmaf(wk, X.f[j], acc[j]);
          }
          float* pp = &sPart[ci*64 + vq*16];
#pragma unroll
          for (int m = 0; m < 4; ++m)
            *(float4*)(pp + 4*m) = make_float4(acc[4*m], acc[4*m+1], acc[4*m+2], acc[4*m+3]);
        }
      }
      __syncthreads();

      // (d) assemble h0 = bias + sum_i partials
      for (int idx = tid; idx < 1024; idx += NT) {
        int c = idx >> 6, v = idx & 63;
        float s = bs[c];
        for (int i = 0; i < in_dim; ++i) s += sPart[(i*16 + c)*64 + v];
        sH[0][idx] = s;
      }
      __syncthreads();

      float g[8];
      const int o_m = tid >> 3, v8 = (tid & 7)*8;   // mlp assignment: 1 o, 8 v
      const int v_p = tid & 63, cq = tid >> 6;      // prop assignment: 1 v, 4 c

      // (e) h1 = 0.05*h0 + 0.95*(h0 @ aT)  ->  sH[1];  G += wm[:,0:16] h0
      {
        float bmv = bm[o_m];
#pragma unroll
        for (int j = 0; j < 8; ++j) g[j] = bmv;
        float pa[4] = {0.f, 0.f, 0.f, 0.f};
        for (int w4 = 0; w4 < 64; w4 += 4) {
          float a0 = sAT[(w4+0)*64 + v_p];
          float a1 = sAT[(w4+1)*64 + v_p];
          float a2 = sAT[(w4+2)*64 + v_p];
          float a3 = sAT[(w4+3)*64 + v_p];
#pragma unroll
          for (int j = 0; j < 4; ++j) {
            float4 h = *(const float4*)&sH[0][(cq*4 + j)*64 + w4];
            pa[j] = fmaf(h.x, a0, pa[j]); pa[j] = fmaf(h.y, a1, pa[j]);
            pa[j] = fmaf(h.z, a2, pa[j]); pa[j] = fmaf(h.w, a3, pa[j]);
          }
        }
#pragma unroll
        for (int j = 0; j < 4; ++j) {
          int c = cq*4 + j;
          sH[1][c*64 + v_p] = fmaf(0.95f, pa[j], 0.05f*sH[0][c*64 + v_p]);
        }
        for (int c = 0; c < 16; ++c) {
          float wv = wm[o_m*48 + c];
          float4 ha = *(const float4*)&sH[0][c*64 + v8];
          float4 hb = *(const float4*)&sH[0][c*64 + v8 + 4];
          g[0]=fmaf(wv,ha.x,g[0]); g[1]=fmaf(wv,ha.y,g[1]); g[2]=fmaf(wv,ha.z,g[2]); g[3]=fmaf(wv,ha.w,g[3]);
          g[4]=fmaf(wv,hb.x,g[4]); g[5]=fmaf(wv,hb.y,g[5]); g[6]=fmaf(wv,hb.z,g[6]); g[7]=fmaf(wv,hb.w,g[7]);
        }
      }
      __syncthreads();

      // (f) G += wm[:,16:32] h1;  h2 = 0.05*h0 + 0.95*(h1 @ aT) overwrites sH[0] (own elements)
      {
        float pa[4] = {0.f, 0.f, 0.f, 0.f};
        for (int w4 = 0; w4 < 64; w4 += 4) {
          float a0 = sAT[(w4+0)*64 + v_p];
          float a1 = sAT[(w4+1)*64 + v_p];
          float a2 = sAT[(w4+2)*64 + v_p];
          float a3 = sAT[(w4+3)*64 + v_p];
#pragma unroll
          for (int j = 0; j < 4; ++j) {
            float4 h = *(const float4*)&sH[1][(cq*4 + j)*64 + w4];
            pa[j] = fmaf(h.x, a0, pa[j]); pa[j] = fmaf(h.y, a1, pa[j]);
            pa[j] = fmaf(h.z, a2, pa[j]); pa[j] = fmaf(h.w, a3, pa[j]);
          }
        }
#pragma unroll
        for (int j = 0; j < 4; ++j) {
          int c = cq*4 + j;
          float h0v = sH[0][c*64 + v_p];
          sH[0][c*64 + v_p] = fmaf(0.95f, pa[j], 0.05f*h0v);
        }
        for (int c = 0; c < 16; ++c) {
          float wv = wm[o_m*48 + 16 + c];
          float4 ha = *(const float4*)&sH[1][c*64 + v8];
          float4 hb = *(const float4*)&sH[1][c*64 + v8 + 4];
          g[0]=fmaf(wv,ha.x,g[0]); g[1]=fmaf(wv,ha.y,g[1]); g[2]=fmaf(wv,ha.z,g[2]); g[3]=fmaf(wv,ha.w,g[3]);
          g[4]=fmaf(wv,hb.x,g[4]); g[5]=fmaf(wv,hb.y,g[5]); g[6]=fmaf(wv,hb.z,g[6]); g[7]=fmaf(wv,hb.w,g[7]);
        }
      }
      __syncthreads();

      // (g) G += wm[:,32:48] h2; exact GELU; store to sG (sPart is dead)
      {
        for (int c = 0; c < 16; ++c) {
          float wv = wm[o_m*48 + 32 + c];
          float4 ha = *(const float4*)&sH[0][c*64 + v8];
          float4 hb = *(const float4*)&sH[0][c*64 + v8 + 4];
          g[0]=fmaf(wv,ha.x,g[0]); g[1]=fmaf(wv,ha.y,g[1]); g[2]=fmaf(wv,ha.z,g[2]); g[3]=fmaf(wv,ha.w,g[3]);
          g[4]=fmaf(wv,hb.x,g[4]); g[5]=fmaf(wv,hb.y,g[5]); g[6]=fmaf(wv,hb.z,g[6]); g[7]=fmaf(wv,hb.w,g[7]);
        }
#pragma unroll
        for (int j = 0; j < 8; ++j) {
          float x = g[j];
          g[j] = 0.5f * x * (1.f + erff(x * 0.70710678118654752f));
        }
        *(float4*)&sG[o_m*64 + v8]     = make_float4(g[0], g[1], g[2], g[3]);
        *(float4*)&sG[o_m*64 + v8 + 4] = make_float4(g[4], g[5], g[6], g[7]);
      }
      __syncthreads();

      // (h) end: E[o2][v] = be + sum_c we[o2][c] G[c][v]
      for (int idx = tid; idx < 384; idx += NT) {
        int o2 = idx >> 6, v = idx & 63;
        float acc = be[o2];
        for (int c = 0; c < 32; ++c) acc = fmaf(we[o2*32 + c], sG[c*64 + v], acc);
        sE[idx] = acc;
      }
      __syncthreads();

      // (i) lin: Y[o2][d] = bl[d] + sum_v E[o2][v] wl[d][v]
      if (tid < 192) {
        const int d = tid;
        const float* wlt = A.wlT + layer*12288;
        float y[6];
        float blv = bl[d];
#pragma unroll
        for (int o2 = 0; o2 < 6; ++o2) y[o2] = blv;
        for (int v4 = 0; v4 < 64; v4 += 4) {
          float4 e[6];
#pragma unroll
          for (int o2 = 0; o2 < 6; ++o2) e[o2] = *(const float4*)&sE[o2*64 + v4];
          float w0 = wlt[(v4+0)*192 + d];
          float w1 = wlt[(v4+1)*192 + d];
          float w2 = wlt[(v4+2)*192 + d];
          float w3 = wlt[(v4+3)*192 + d];
#pragma unroll
          for (int o2 = 0; o2 < 6; ++o2) {
            y[o2] = fmaf(e[o2].x, w0, y[o2]); y[o2] = fmaf(e[o2].y, w1, y[o2]);
            y[o2] = fmaf(e[o2].z, w2, y[o2]); y[o2] = fmaf(e[o2].w, w3, y[o2]);
          }
        }
#pragma unroll
        for (int o2 = 0; o2 < 6; ++o2) sY[o2*192 + d] = y[o2];
      }
      __syncthreads();

      // (j) LayerNorm per (o2) row over 192, in place -> gate values
      if (tid < 192) {
        const int r = tid >> 5, l32 = tid & 31;
        float sm = 0.f, sq = 0.f;
#pragma unroll
        for (int m = 0; m < 6; ++m) {
          float v = sY[r*192 + l32 + 32*m];
          sm += v; sq = fmaf(v, v, sq);
        }
#pragma unroll
        for (int off = 16; off >= 1; off >>= 1) {
          sm += __shfl_xor(sm, off);
          sq += __shfl_xor(sq, off);
        }
        float mu  = sm * (1.f/192.f);
        float var = sq * (1.f/192.f) - mu*mu;
        float rstd = rsqrtf(fmaxf(var, 0.f) + 1e-5f);
#pragma unroll
        for (int m = 0; m < 6; ++m) {
          int d = l32 + 32*m;
          float v = (sY[r*192 + d] - mu) * rstd;
          sY[r*192 + d] = fmaf(v, gm[d], bt[d]);
        }
      }
      __syncthreads();

      // (k) gates, state update, outputs, publish
      if (tid < 192) {
        const int d = tid;
        float ugr = 1.f/(1.f + expf(-sY[0*192 + d]));
        float ogr = 1.f/(1.f + expf(-sY[1*192 + d]));
        float ugc = 1.f/(1.f + expf(-sY[2*192 + d]));
        float ogc = 1.f/(1.f + expf(-sY[3*192 + d]));
        float igr = tanhf(sY[4*192 + d]);
        float igc = tanhf(sY[5*192 + d]);
        float hr = sCIN[d], hc = sCIN[192 + d];
        float hrn = tanhf(fmaf(ugr, igr, (1.f - ugr)*hr)) * ogr;
        float hcn = tanhf(fmaf(ugc, igc, (1.f - ugc)*hc)) * ogc;
        sCIN[d] = hrn;
        __hip_atomic_store(&A.HCOL[((size_t)(S & 31)*192 + n)*192 + d], hcn,
                           __ATOMIC_RELAXED, __HIP_MEMORY_SCOPE_AGENT);
        float* oa = A.out_all + ((size_t)n*71 + t)*384;
        if (layer == 0) {
          oa[d] = hrn; oa[192 + d] = hcn;
        } else {
          // residual: layer-0 out was staged into sCIN[384..768) in stage (a)
          oa[d]       = hrn + sCIN[384 + d];
          oa[192 + d] = hcn + sCIN[576 + d];
        }
        if (t == 47 + w)
          A.out_hrow[(((size_t)b*2 + layer)*24 + w)*192 + d] = hrn;
        if (w == 23 && t >= 23)
          A.out_hcol[(((size_t)b*2 + layer)*48 + (t - 23))*192 + d] = hcn;
      }
      __syncthreads();
      if (tid == 0) {
        __threadfence();
        __hip_atomic_store(&A.flags[n], S + 1, __ATOMIC_RELEASE, __HIP_MEMORY_SCOPE_AGENT);
      }
    } // t
    __syncthreads();
  } // layer
}

extern "C" void kernel_launch(void* const* d_in, const int* in_sizes, int n_in,
                              void* d_out, int out_size, void* d_ws, size_t ws_size,
                              hipStream_t stream) {
  (void)in_sizes; (void)n_in; (void)out_size; (void)ws_size;
  char* ws = (char*)d_ws;
  int*   flags = (int*)ws;                       // 1,024 B
  float* AT    = (float*)(ws + 1024);            // 32,768 B
  float* wlT   = (float*)(ws + 33792);           // 98,304 B
  float* HCOL  = (float*)(ws + 132096);          // 4,718,592 B (ring 32, fp32)
  // total ws: 4,850,688 B

  hipMemsetAsync(flags, 0, 1024, stream);
  prep_kernel<<<4, 256, 0, stream>>>(
      (const float*)d_in[1],  (const float*)d_in[2],
      (const float*)d_in[13], (const float*)d_in[14],
      (const float*)d_in[9],  (const float*)d_in[21],
      AT, wlT);

  SeqArgs A;
  A.input    = (const float*)d_in[0];
  A.w_start0 = (const float*)d_in[3];  A.b_start0 = (const float*)d_in[4];
  A.w_mlp0   = (const float*)d_in[5];  A.b_mlp0   = (const float*)d_in[6];
  A.w_end0   = (const float*)d_in[7];  A.b_end0   = (const float*)d_in[8];
  A.b_lin0   = (const float*)d_in[10]; A.gamma0   = (const float*)d_in[11]; A.beta0 = (const float*)d_in[12];
  A.w_start1 = (const float*)d_in[15]; A.b_start1 = (const float*)d_in[16];
  A.w_mlp1   = (const float*)d_in[17]; A.b_mlp1   = (const float*)d_in[18];
  A.w_end1   = (const float*)d_in[19]; A.b_end1   = (const float*)d_in[20];
  A.b_lin1   = (const float*)d_in[22]; A.gamma1   = (const float*)d_in[23]; A.beta1 = (const float*)d_in[24];
  A.AT = AT; A.wlT = wlT; A.HCOL = HCOL; A.flags = flags;
  A.out_all  = (float*)d_out;
  A.out_hrow = (float*)d_out + 5234688;
  A.out_hcol = (float*)d_out + 5308416;

  seq_kernel<<<192, NT, 0, stream>>>(A);
}

// Round 5
// 2871.628 us; speedup vs baseline: 1.2581x; 1.2581x over previous
//
#include <hip/hip_runtime.h>
#include <hip/hip_bf16.h>

#define NT 256
typedef unsigned short u16;

__device__ __forceinline__ u16 tobf(float x) {
  union { __hip_bfloat16 h; u16 u; } cv;
  cv.h = __float2bfloat16(x);
  return cv.u;
}
__device__ __forceinline__ float frombf(u16 u) {
  return __uint_as_float(((unsigned)u) << 16);
}
__device__ __forceinline__ float sigf(float x) {
  return __builtin_amdgcn_rcpf(1.f + __builtin_amdgcn_exp2f(-1.4426950408889634f * x));
}
__device__ __forceinline__ float tanh_fast(float x) {
  return 1.f - 2.f * __builtin_amdgcn_rcpf(1.f + __builtin_amdgcn_exp2f(2.8853900817779268f * x));
}

struct SeqArgs {
  const float* input;
  const float* nv1_0; const float* nv2_0; const float* nv1_1; const float* nv2_1;
  const float* w_start0; const float* b_start0; const float* w_mlp0; const float* b_mlp0;
  const float* w_end0;   const float* b_end0;   const float* w_lin0; const float* b_lin0;
  const float* gamma0;   const float* beta0;
  const float* w_start1; const float* b_start1; const float* w_mlp1; const float* b_mlp1;
  const float* w_end1;   const float* b_end1;   const float* w_lin1; const float* b_lin1;
  const float* gamma1;   const float* beta1;
  float* HCOL;   // ws ring [32][192][192] fp32
  int*   flags;  // ws [192*32] ints, stride 32 (128B) per row
  float* out_all; float* out_hrow; float* out_hcol;
};

__global__ __launch_bounds__(NT, 1) void seq_kernel(SeqArgs A) {
  const int n = blockIdx.x, w = n >> 3, b = n & 7, tid = threadIdx.x;
  const int pred = (n + 184) % 192;   // n-8 mod 192

  __shared__ __align__(16) float sCIN[768];     // [h_row | h_col | x(<=2ch)]
  __shared__ __align__(16) u16   sWS[64 * 132]; // conv weights bf16, row=i*16+c
  __shared__ __align__(16) float sAT[4096];     // aT[w*64+v]
  __shared__ __align__(16) float sH[2][1024];   // [c*64+v]
  __shared__ __align__(16) float sAbuf[4928];
  float* const sPart = sAbuf;          // [0..3071] pre-conv partials (P*16*64)
  float* const sG    = sAbuf;          // [0..2047]
  float* const sE    = sAbuf + 2048;   // [2048..2431]
  float* const sY    = sAbuf;          // [0..1151]
  float* const smWE  = sAbuf + 3072;   // 192
  float* const smBE  = sAbuf + 3264;   // 6
  float* const smWM  = sAbuf + 3328;   // 32*50 (stride 50: bank-conflict-free)

  for (int layer = 0; layer < 2; ++layer) {
    const int in_dim = 3 + layer;
    const int P = in_dim - 1;  // pre channels: h_row + x-channels
    const float* nv1    = layer ? A.nv1_1    : A.nv1_0;
    const float* nv2    = layer ? A.nv2_1    : A.nv2_0;
    const float* wstart = layer ? A.w_start1 : A.w_start0;
    const float* bs     = layer ? A.b_start1 : A.b_start0;
    const float* wm     = layer ? A.w_mlp1   : A.w_mlp0;
    const float* bm     = layer ? A.b_mlp1   : A.b_mlp0;
    const float* we     = layer ? A.w_end1   : A.w_end0;
    const float* be     = layer ? A.b_end1   : A.b_end0;
    const float* wl     = layer ? A.w_lin1   : A.w_lin0;
    const float* bl     = layer ? A.b_lin1   : A.b_lin0;
    const float* gm     = layer ? A.gamma1   : A.gamma0;
    const float* bt     = layer ? A.beta1    : A.beta0;

    // ---- layer init: adjacency (scores -> softmax -> sAT), weights, regs ----
    for (int idx = tid; idx < 4096; idx += NT) {
      int v = idx >> 6, ww = idx & 63;
      float s = 0.f;
      for (int j = 0; j < 40; ++j) s = fmaf(nv1[v*40 + j], nv2[j*64 + ww], s);
      sAbuf[idx] = fmaxf(s, 0.f);
    }
    __syncthreads();
    if (tid < 64) {
      const int v = tid;
      float m = -1e30f;
      for (int ww = 0; ww < 64; ++ww) m = fmaxf(m, sAbuf[v*64 + ww]);
      float s = 0.f;
      for (int ww = 0; ww < 64; ++ww) { float e = expf(sAbuf[v*64 + ww] - m); sAbuf[v*64 + ww] = e; s += e; }
      float inv = 1.f / s, rs = 1.f;
      for (int ww = 0; ww < 64; ++ww) rs += sAbuf[v*64 + ww] * inv;
      float irs = 1.f / rs;
      for (int ww = 0; ww < 64; ++ww) {
        float a = sAbuf[v*64 + ww] * inv + ((ww == v) ? 1.f : 0.f);
        sAT[ww*64 + v] = a * irs;
      }
    }
    __syncthreads();  // sAT ready; scores region dead
    for (int idx = tid; idx < 16*in_dim*132; idx += NT) {
      int row = idx / 132, k = idx - row*132;
      sWS[idx] = (k < 129) ? tobf(wstart[((row & 15)*in_dim + (row >> 4))*129 + k]) : (u16)0;
    }
    for (int idx = tid; idx < 1536; idx += NT) { int o = idx/48, c = idx - o*48; smWM[o*50 + c] = wm[idx]; }
    for (int idx = tid; idx < 192; idx += NT) smWE[idx] = we[idx];
    if (tid < 6) smBE[tid] = be[tid];
    for (int d = tid; d < 384; d += NT) sCIN[d] = 0.f;

    const int o_m = tid >> 3, v8 = (tid & 7)*8;
    const int v_p = tid & 63, cq = tid >> 6;
    const float bmv = bm[o_m];
    float blv = 0.f, gmv = 1.f, btv = 0.f;
    if (tid < 192) { blv = bl[tid]; gmv = gm[tid]; btv = bt[tid]; }
    float bs_r[4];
#pragma unroll
    for (int m = 0; m < 4; ++m) bs_r[m] = bs[(tid >> 6) + 4*m];
    __syncthreads();

    // ---- pre-phase: stage x(t), conv of {h_row, x} channels, assemble h0pre ----
    auto pre_phase = [&](int t) {
      if (layer == 0) {
        int o = t - w;
        if (o >= 0 && o < 48) {
          const float* xr = A.input + (((size_t)(b*24 + w)*48 + o)*192);
          for (int d = tid; d < 192; d += NT) sCIN[384 + d] = xr[d];
        } else {
          for (int d = tid; d < 192; d += NT) sCIN[384 + d] = 0.f;
        }
      } else {
        const float* xr = A.out_all + ((size_t)n*71 + t)*384;
        for (int d = tid; d < 384; d += NT) sCIN[384 + d] = xr[d];
      }
      __syncthreads();
      {
        const int ci = tid >> 2, vq = tid & 3;
        const int p = ci >> 4, c = ci & 15;
        if (p < P) {
          const int ich = (p == 0) ? 0 : (p + 1);
          float acc[16];
#pragma unroll
          for (int j = 0; j < 16; ++j) acc[j] = 0.f;
          const float* xin = (p == 0) ? &sCIN[vq*16] : &sCIN[384 + (p-1)*192 + vq*16];
          const u16* wrow = &sWS[(ich*16 + c)*132];
          for (int k4 = 0; k4 < 128; k4 += 4) {
            ushort4 wu = *(const ushort4*)(wrow + k4);
            float w0 = frombf(wu.x), w1 = frombf(wu.y), w2 = frombf(wu.z), w3 = frombf(wu.w);
            union { float4 v4[5]; float f[20]; } X;
#pragma unroll
            for (int m = 0; m < 5; ++m) X.v4[m] = *(const float4*)(xin + k4 + 4*m);
#pragma unroll
            for (int j = 0; j < 16; ++j) {
              acc[j] = fmaf(w0, X.f[j],   acc[j]);
              acc[j] = fmaf(w1, X.f[j+1], acc[j]);
              acc[j] = fmaf(w2, X.f[j+2], acc[j]);
              acc[j] = fmaf(w3, X.f[j+3], acc[j]);
            }
          }
          {
            float wk = frombf(wrow[128]);
            union { float4 v4[4]; float f[16]; } X;
#pragma unroll
            for (int m = 0; m < 4; ++m) X.v4[m] = *(const float4*)(xin + 128 + 4*m);
#pragma unroll
            for (int j = 0; j < 16; ++j) acc[j] = fmaf(wk, X.f[j], acc[j]);
          }
          float* pp = &sPart[(p*16 + c)*64 + vq*16];
#pragma unroll
          for (int m = 0; m < 4; ++m)
            *(float4*)(pp + 4*m) = make_float4(acc[4*m], acc[4*m+1], acc[4*m+2], acc[4*m+3]);
        }
      }
      __syncthreads();
      {
        int m = 0;
        for (int idx = tid; idx < 1024; idx += NT, ++m) {
          int c = idx >> 6, v = idx & 63;
          float s = bs_r[m];
          for (int p = 0; p < P; ++p) s += sPart[(p*16 + c)*64 + v];
          sH[0][idx] = s;
        }
      }
      __syncthreads();
    };
    pre_phase(0);

    for (int t = 0; t < 71; ++t) {
      const int S = layer*71 + t;

      // ---- dependent path ----
      if (t > 0) {
        if (tid == 0) {
          while (__hip_atomic_load(&A.flags[pred*32], __ATOMIC_ACQUIRE, __HIP_MEMORY_SCOPE_AGENT) < S)
            __builtin_amdgcn_s_sleep(1);
        }
        __syncthreads();  // B1
        float* hc = A.HCOL + ((size_t)((S-1) & 31)*192 + pred)*192;
        for (int d = tid; d < 192; d += NT)
          sCIN[192 + d] = __hip_atomic_load(&hc[d], __ATOMIC_RELAXED, __HIP_MEMORY_SCOPE_AGENT);
        __syncthreads();  // B2
      }

      // h_col conv, in-place accumulate into sH[0] (thread owns (c, vg*4..+3))
      {
        const int c = tid >> 4, vg = tid & 15;
        const float* xin = &sCIN[192 + vg*4];
        const u16* wrow = &sWS[(16 + c)*132];
        float4 a4 = *(const float4*)&sH[0][c*64 + vg*4];
        float a0 = a4.x, a1 = a4.y, a2 = a4.z, a3 = a4.w;
        float4 xc = *(const float4*)xin;
        for (int k4 = 0; k4 < 128; k4 += 4) {
          ushort4 wu = *(const ushort4*)(wrow + k4);
          float w0 = frombf(wu.x), w1 = frombf(wu.y), w2 = frombf(wu.z), w3 = frombf(wu.w);
          float4 xn = *(const float4*)(xin + k4 + 4);
          a0 = fmaf(w3, xc.w, fmaf(w2, xc.z, fmaf(w1, xc.y, fmaf(w0, xc.x, a0))));
          a1 = fmaf(w3, xn.x, fmaf(w2, xc.w, fmaf(w1, xc.z, fmaf(w0, xc.y, a1))));
          a2 = fmaf(w3, xn.y, fmaf(w2, xn.x, fmaf(w1, xc.w, fmaf(w0, xc.z, a2))));
          a3 = fmaf(w3, xn.z, fmaf(w2, xn.y, fmaf(w1, xn.x, fmaf(w0, xc.w, a3))));
          xc = xn;
        }
        float wk = frombf(wrow[128]);
        a0 = fmaf(wk, xc.x, a0); a1 = fmaf(wk, xc.y, a1);
        a2 = fmaf(wk, xc.z, a2); a3 = fmaf(wk, xc.w, a3);
        *(float4*)&sH[0][c*64 + vg*4] = make_float4(a0, a1, a2, a3);
      }
      __syncthreads();  // B3

      float g[8];
      // (e) h1 = 0.05 h0 + 0.95 (h0 @ aT); G += wm[:,0:16] h0
      {
#pragma unroll
        for (int j = 0; j < 8; ++j) g[j] = bmv;
        float pa[4] = {0.f, 0.f, 0.f, 0.f};
        for (int w4 = 0; w4 < 64; w4 += 4) {
          float a0 = sAT[(w4+0)*64 + v_p];
          float a1 = sAT[(w4+1)*64 + v_p];
          float a2 = sAT[(w4+2)*64 + v_p];
          float a3 = sAT[(w4+3)*64 + v_p];
#pragma unroll
          for (int j = 0; j < 4; ++j) {
            float4 h = *(const float4*)&sH[0][(cq*4 + j)*64 + w4];
            pa[j] = fmaf(h.x, a0, pa[j]); pa[j] = fmaf(h.y, a1, pa[j]);
            pa[j] = fmaf(h.z, a2, pa[j]); pa[j] = fmaf(h.w, a3, pa[j]);
          }
        }
#pragma unroll
        for (int j = 0; j < 4; ++j) {
          int c = cq*4 + j;
          sH[1][c*64 + v_p] = fmaf(0.95f, pa[j], 0.05f*sH[0][c*64 + v_p]);
        }
        for (int c = 0; c < 16; ++c) {
          float wv = smWM[o_m*50 + c];
          float4 ha = *(const float4*)&sH[0][c*64 + v8];
          float4 hb = *(const float4*)&sH[0][c*64 + v8 + 4];
          g[0]=fmaf(wv,ha.x,g[0]); g[1]=fmaf(wv,ha.y,g[1]); g[2]=fmaf(wv,ha.z,g[2]); g[3]=fmaf(wv,ha.w,g[3]);
          g[4]=fmaf(wv,hb.x,g[4]); g[5]=fmaf(wv,hb.y,g[5]); g[6]=fmaf(wv,hb.z,g[6]); g[7]=fmaf(wv,hb.w,g[7]);
        }
      }
      __syncthreads();  // B4

      // (f) h2 = 0.05 h0 + 0.95 (h1 @ aT) in place; G += wm[:,16:32] h1
      {
        float pa[4] = {0.f, 0.f, 0.f, 0.f};
        for (int w4 = 0; w4 < 64; w4 += 4) {
          float a0 = sAT[(w4+0)*64 + v_p];
          float a1 = sAT[(w4+1)*64 + v_p];
          float a2 = sAT[(w4+2)*64 + v_p];
          float a3 = sAT[(w4+3)*64 + v_p];
#pragma unroll
          for (int j = 0; j < 4; ++j) {
            float4 h = *(const float4*)&sH[1][(cq*4 + j)*64 + w4];
            pa[j] = fmaf(h.x, a0, pa[j]); pa[j] = fmaf(h.y, a1, pa[j]);
            pa[j] = fmaf(h.z, a2, pa[j]); pa[j] = fmaf(h.w, a3, pa[j]);
          }
        }
#pragma unroll
        for (int j = 0; j < 4; ++j) {
          int c = cq*4 + j;
          float h0v = sH[0][c*64 + v_p];
          sH[0][c*64 + v_p] = fmaf(0.95f, pa[j], 0.05f*h0v);
        }
        for (int c = 0; c < 16; ++c) {
          float wv = smWM[o_m*50 + 16 + c];
          float4 ha = *(const float4*)&sH[1][c*64 + v8];
          float4 hb = *(const float4*)&sH[1][c*64 + v8 + 4];
          g[0]=fmaf(wv,ha.x,g[0]); g[1]=fmaf(wv,ha.y,g[1]); g[2]=fmaf(wv,ha.z,g[2]); g[3]=fmaf(wv,ha.w,g[3]);
          g[4]=fmaf(wv,hb.x,g[4]); g[5]=fmaf(wv,hb.y,g[5]); g[6]=fmaf(wv,hb.z,g[6]); g[7]=fmaf(wv,hb.w,g[7]);
        }
      }
      __syncthreads();  // B5

      // (g) G += wm[:,32:48] h2; exact GELU; -> sG
      {
        for (int c = 0; c < 16; ++c) {
          float wv = smWM[o_m*50 + 32 + c];
          float4 ha = *(const float4*)&sH[0][c*64 + v8];
          float4 hb = *(const float4*)&sH[0][c*64 + v8 + 4];
          g[0]=fmaf(wv,ha.x,g[0]); g[1]=fmaf(wv,ha.y,g[1]); g[2]=fmaf(wv,ha.z,g[2]); g[3]=fmaf(wv,ha.w,g[3]);
          g[4]=fmaf(wv,hb.x,g[4]); g[5]=fmaf(wv,hb.y,g[5]); g[6]=fmaf(wv,hb.z,g[6]); g[7]=fmaf(wv,hb.w,g[7]);
        }
#pragma unroll
        for (int j = 0; j < 8; ++j) {
          float x = g[j];
          g[j] = 0.5f * x * (1.f + erff(x * 0.70710678118654752f));
        }
        *(float4*)&sG[o_m*64 + v8]     = make_float4(g[0], g[1], g[2], g[3]);
        *(float4*)&sG[o_m*64 + v8 + 4] = make_float4(g[4], g[5], g[6], g[7]);
      }
      __syncthreads();  // B6

      // (h) E = be + we @ G
      for (int idx = tid; idx < 384; idx += NT) {
        int o2 = idx >> 6, v = idx & 63;
        float acc = smBE[o2];
        for (int c = 0; c < 32; ++c) acc = fmaf(smWE[o2*32 + c], sG[c*64 + v], acc);
        sE[idx] = acc;
      }
      __syncthreads();  // B7

      // (i) Y = bl + E @ wl^T (wl read directly as float4 rows)
      if (tid < 192) {
        const int d = tid;
        const float4* wrow = (const float4*)(wl + d*64);
        float y0=blv, y1=blv, y2=blv, y3=blv, y4=blv, y5=blv;
        for (int q = 0; q < 16; ++q) {
          float4 wv = wrow[q];
          float4 e0 = *(const float4*)&sE[0*64 + q*4];
          float4 e1 = *(const float4*)&sE[1*64 + q*4];
          float4 e2 = *(const float4*)&sE[2*64 + q*4];
          float4 e3 = *(const float4*)&sE[3*64 + q*4];
          float4 e4 = *(const float4*)&sE[4*64 + q*4];
          float4 e5 = *(const float4*)&sE[5*64 + q*4];
          y0 = fmaf(e0.x,wv.x, fmaf(e0.y,wv.y, fmaf(e0.z,wv.z, fmaf(e0.w,wv.w, y0))));
          y1 = fmaf(e1.x,wv.x, fmaf(e1.y,wv.y, fmaf(e1.z,wv.z, fmaf(e1.w,wv.w, y1))));
          y2 = fmaf(e2.x,wv.x, fmaf(e2.y,wv.y, fmaf(e2.z,wv.z, fmaf(e2.w,wv.w, y2))));
          y3 = fmaf(e3.x,wv.x, fmaf(e3.y,wv.y, fmaf(e3.z,wv.z, fmaf(e3.w,wv.w, y3))));
          y4 = fmaf(e4.x,wv.x, fmaf(e4.y,wv.y, fmaf(e4.z,wv.z, fmaf(e4.w,wv.w, y4))));
          y5 = fmaf(e5.x,wv.x, fmaf(e5.y,wv.y, fmaf(e5.z,wv.z, fmaf(e5.w,wv.w, y5))));
        }
        sY[0*192+d]=y0; sY[1*192+d]=y1; sY[2*192+d]=y2;
        sY[3*192+d]=y3; sY[4*192+d]=y4; sY[5*192+d]=y5;
      }
      __syncthreads();  // B8

      // (j1) LN stats -> sH[1][0..13]
      if (tid < 192) {
        const int r = tid >> 5, l32 = tid & 31;
        float sm = 0.f, sq = 0.f;
#pragma unroll
        for (int m = 0; m < 6; ++m) {
          float v = sY[r*192 + l32 + 32*m];
          sm += v; sq = fmaf(v, v, sq);
        }
#pragma unroll
        for (int off = 16; off >= 1; off >>= 1) {
          sm += __shfl_xor(sm, off);
          sq += __shfl_xor(sq, off);
        }
        if (l32 == 0) {
          float mu = sm * (1.f/192.f);
          float var = sq * (1.f/192.f) - mu*mu;
          sH[1][r] = mu;
          sH[1][8 + r] = rsqrtf(fmaxf(var, 0.f) + 1e-5f);
        }
      }
      __syncthreads();  // B9

      float hcn = 0.f;
      // (k1) col gates -> hcn -> HCOL
      if (tid < 192) {
        const int d = tid;
        float y2 = fmaf((sY[2*192+d] - sH[1][2]) * sH[1][10], gmv, btv);
        float y3 = fmaf((sY[3*192+d] - sH[1][3]) * sH[1][11], gmv, btv);
        float y5 = fmaf((sY[5*192+d] - sH[1][5]) * sH[1][13], gmv, btv);
        float ugc = sigf(y2), ogc = sigf(y3), igc = tanh_fast(y5);
        float hc = sCIN[192 + d];
        hcn = tanh_fast(fmaf(ugc, igc, (1.f - ugc)*hc)) * ogc;
        __hip_atomic_store(&A.HCOL[((size_t)(S & 31)*192 + n)*192 + d], hcn,
                           __ATOMIC_RELAXED, __HIP_MEMORY_SCOPE_AGENT);
      }
      __syncthreads();  // B10
      if (tid == 0) {
        __threadfence();
        __hip_atomic_store(&A.flags[n*32], S + 1, __ATOMIC_RELEASE, __HIP_MEMORY_SCOPE_AGENT);
      }
      // (k2) row gates + outputs (off critical path)
      if (tid < 192) {
        const int d = tid;
        float y0 = fmaf((sY[0*192+d] - sH[1][0]) * sH[1][8],  gmv, btv);
        float y1 = fmaf((sY[1*192+d] - sH[1][1]) * sH[1][9],  gmv, btv);
        float y4 = fmaf((sY[4*192+d] - sH[1][4]) * sH[1][12], gmv, btv);
        float ugr = sigf(y0), ogr = sigf(y1), igr = tanh_fast(y4);
        float hr = sCIN[d];
        float hrn = tanh_fast(fmaf(ugr, igr, (1.f - ugr)*hr)) * ogr;
        sCIN[d] = hrn;
        float* oa = A.out_all + ((size_t)n*71 + t)*384;
        if (layer == 0) { oa[d] = hrn; oa[192 + d] = hcn; }
        else           { oa[d] = hrn + sCIN[384 + d]; oa[192 + d] = hcn + sCIN[576 + d]; }
        if (t == 47 + w)
          A.out_hrow[(((size_t)b*2 + layer)*24 + w)*192 + d] = hrn;
        if (w == 23 && t >= 23)
          A.out_hcol[(((size_t)b*2 + layer)*48 + (t - 23))*192 + d] = hcn;
      }
      __syncthreads();  // B11
      if (t < 70) pre_phase(t + 1);
    } // t
    __syncthreads();
  } // layer
}

extern "C" void kernel_launch(void* const* d_in, const int* in_sizes, int n_in,
                              void* d_out, int out_size, void* d_ws, size_t ws_size,
                              hipStream_t stream) {
  (void)in_sizes; (void)n_in; (void)out_size; (void)ws_size;
  char* ws = (char*)d_ws;
  int*   flags = (int*)ws;                 // 24,576 B (192 x 128B)
  float* HCOL  = (float*)(ws + 24576);     // 4,718,592 B
  // total ws: 4,743,168 B

  hipMemsetAsync(flags, 0, 24576, stream);

  SeqArgs A;
  A.input    = (const float*)d_in[0];
  A.nv1_0    = (const float*)d_in[1];  A.nv2_0 = (const float*)d_in[2];
  A.w_start0 = (const float*)d_in[3];  A.b_start0 = (const float*)d_in[4];
  A.w_mlp0   = (const float*)d_in[5];  A.b_mlp0   = (const float*)d_in[6];
  A.w_end0   = (const float*)d_in[7];  A.b_end0   = (const float*)d_in[8];
  A.w_lin0   = (const float*)d_in[9];  A.b_lin0   = (const float*)d_in[10];
  A.gamma0   = (const float*)d_in[11]; A.beta0    = (const float*)d_in[12];
  A.nv1_1    = (const float*)d_in[13]; A.nv2_1 = (const float*)d_in[14];
  A.w_start1 = (const float*)d_in[15]; A.b_start1 = (const float*)d_in[16];
  A.w_mlp1   = (const float*)d_in[17]; A.b_mlp1   = (const float*)d_in[18];
  A.w_end1   = (const float*)d_in[19]; A.b_end1   = (const float*)d_in[20];
  A.w_lin1   = (const float*)d_in[21]; A.b_lin1   = (const float*)d_in[22];
  A.gamma1   = (const float*)d_in[23]; A.beta1    = (const float*)d_in[24];
  A.HCOL = HCOL; A.flags = flags;
  A.out_all  = (float*)d_out;
  A.out_hrow = (float*)d_out + 5234688;
  A.out_hcol = (float*)d_out + 5308416;

  seq_kernel<<<192, NT, 0, stream>>>(A);
}